// Round 7
// baseline (210.418 us; speedup 1.0000x reference)
//
#include <hip/hip_runtime.h>

#define NN 100000
#define NE 3200000
#define FEAT 128
#define EMBED 128

typedef __attribute__((ext_vector_type(8))) __bf16 bf16x8;
typedef __attribute__((ext_vector_type(8))) unsigned short ushort8;
typedef __attribute__((ext_vector_type(4))) float f32x4;

static __device__ __forceinline__ unsigned short f2bf(float f) {
    unsigned u = __float_as_uint(f);
    return (unsigned short)((u + 0x7FFFu + ((u >> 16) & 1u)) >> 16);  // RNE
}

// ---------------------------------------------------------------------------
// w fp32 [128][128] -> bf16 bits (ushort) [128][128]
// ---------------------------------------------------------------------------
__global__ void convert_w(const float* __restrict__ w, unsigned short* __restrict__ wbf) {
    int i = blockIdx.x * 256 + threadIdx.x;
    if (i < EMBED * FEAT) wbf[i] = f2bf(w[i]);
}

// ---------------------------------------------------------------------------
// h_bf[n][e] = bf16( sum_f x[n][f] * w[e][f] ), via mfma_f32_16x16x32_bf16.
// (unchanged -- memory-bound, ~20 us)
// ---------------------------------------------------------------------------
__global__ __launch_bounds__(256)
void gemm_xwT(const float* __restrict__ x, const unsigned short* __restrict__ wbf,
              unsigned short* __restrict__ hbf) {
    int wave = blockIdx.x * 4 + (threadIdx.x >> 6);
    long row0 = (long)wave * 16;
    if (row0 >= NN) return;
    int lane = threadIdx.x & 63;
    int r = lane & 15, kg = lane >> 4;

    const float4* x4 = (const float4*)x;  // [row*32 + fc4]
    const bf16x8* wb = (const bf16x8*)wbf;

    bf16x8 afr[4];
#pragma unroll
    for (int ks = 0; ks < 4; ++ks) {
        long base = (row0 + r) * 32 + ks * 8 + kg * 2;
        float4 v0 = x4[base];
        float4 v1 = x4[base + 1];
        float xf[8] = {v0.x, v0.y, v0.z, v0.w, v1.x, v1.y, v1.z, v1.w};
        ushort8 au;
#pragma unroll
        for (int e = 0; e < 8; ++e) au[e] = f2bf(xf[e]);
        afr[ks] = __builtin_bit_cast(bf16x8, au);
    }

    f32x4 acc[8];
#pragma unroll
    for (int nt = 0; nt < 8; ++nt) acc[nt] = (f32x4){0.f, 0.f, 0.f, 0.f};

#pragma unroll
    for (int nt = 0; nt < 8; ++nt) {
#pragma unroll
        for (int ks = 0; ks < 4; ++ks) {
            bf16x8 b = wb[(nt * 16 + r) * 16 + ks * 4 + kg];
            acc[nt] = __builtin_amdgcn_mfma_f32_16x16x32_bf16(afr[ks], b, acc[nt], 0, 0, 0);
        }
    }

#pragma unroll
    for (int nt = 0; nt < 8; ++nt) {
#pragma unroll
        for (int reg = 0; reg < 4; ++reg) {
            hbf[(row0 + kg * 4 + reg) * 128 + nt * 16 + r] = f2bf(acc[nt][reg]);
        }
    }
}

// ---------------------------------------------------------------------------
// CSR row offsets from sorted edge_dst via per-node lower_bound.
// ---------------------------------------------------------------------------
__global__ void build_rowptr(const int* __restrict__ dst, int* __restrict__ rowptr) {
    int n = blockIdx.x * blockDim.x + threadIdx.x;
    if (n > NN) return;
    int lo = 0, hi = NE;
    while (lo < hi) {
        int mid = (lo + hi) >> 1;
        if (dst[mid] < n) lo = mid + 1; else hi = mid;
    }
    rowptr[n] = lo;
}

// ---------------------------------------------------------------------------
// Column-sliced gather, XCD-pinned: slice s covers h cols [s*64, s*64+64)
// (128 B/row -> full-line granule, no L1-fill amplification). Slice working
// set = 12.8 MB, confined to a 4-XCD group (16 MB L2) via blockIdx mapping:
//   xcd = blockIdx%8 (HW round-robin heuristic), slice = xcd>>2,
//   node-block = (blockIdx>>3)*4 + (xcd&3).
// One wave per (node, slice): lane = (edge slot q=l>>3, col-quad c=l&7);
// one global_load_dwordx4 = 8 edge-rows x 128 B = 1 KB/instr (same instr
// count as R4). Metadata via wave-uniform scalar loads + cndmask select.
// Combine: 3 shfl_xor rounds; q==0 lanes store their 64-col half.
// Each out element written exactly once (covers poisoned d_out).
// ---------------------------------------------------------------------------
#define CONS(vj, wjv)                                                         \
    acc[0] += wjv * __uint_as_float(vj.x << 16);                              \
    acc[1] += wjv * __uint_as_float(vj.x & 0xFFFF0000u);                      \
    acc[2] += wjv * __uint_as_float(vj.y << 16);                              \
    acc[3] += wjv * __uint_as_float(vj.y & 0xFFFF0000u);                      \
    acc[4] += wjv * __uint_as_float(vj.z << 16);                              \
    acc[5] += wjv * __uint_as_float(vj.z & 0xFFFF0000u);                      \
    acc[6] += wjv * __uint_as_float(vj.w << 16);                              \
    acc[7] += wjv * __uint_as_float(vj.w & 0xFFFF0000u);

#define SEL8(r_, a0, a1, a2, a3, a4, a5, a6, a7)                              \
    (q == 0 ? a0 : q == 1 ? a1 : q == 2 ? a2 : q == 3 ? a3 :                  \
     q == 4 ? a4 : q == 5 ? a5 : q == 6 ? a6 : a7)

__global__ __launch_bounds__(256)
void aggregate(const unsigned int* __restrict__ h32, const float* __restrict__ ew,
               const int* __restrict__ src, const int* __restrict__ rowptr,
               float* __restrict__ out) {
    unsigned bid = blockIdx.x;
    unsigned x = bid & 7u;                    // XCD id (round-robin heuristic)
    unsigned slice = x >> 2;                  // 0: cols 0-63, 1: cols 64-127
    unsigned nbIdx = (bid >> 3) * 4 + (x & 3);
    int wid = (int)(nbIdx * 4 + (threadIdx.x >> 6));
    int lane = threadIdx.x & 63;
    if (wid >= NN) return;
    int start = __builtin_amdgcn_readfirstlane(rowptr[wid]);
    int end   = __builtin_amdgcn_readfirstlane(rowptr[wid + 1]);

    int q = lane >> 3;       // edge slot 0..7
    int c = lane & 7;        // uint4 index within 64-col slice
    const uint4* h4 = (const uint4*)h32;     // row stride 16 uint4
    unsigned cbase = slice * 8u + (unsigned)c;

    float acc[8];
#pragma unroll
    for (int j = 0; j < 8; ++j) acc[j] = 0.f;

    int i = start;
    int nfull = (end - start) >> 3;
#pragma unroll 2
    for (int b = 0; b < nfull; ++b, i += 8) {
        int s0 = src[i],     s1 = src[i + 1], s2 = src[i + 2], s3 = src[i + 3];
        int s4 = src[i + 4], s5 = src[i + 5], s6 = src[i + 6], s7 = src[i + 7];
        float w0 = ew[i],     w1 = ew[i + 1], w2 = ew[i + 2], w3 = ew[i + 3];
        float w4 = ew[i + 4], w5 = ew[i + 5], w6 = ew[i + 6], w7 = ew[i + 7];
        int   si = SEL8(q, s0, s1, s2, s3, s4, s5, s6, s7);
        float wi = SEL8(q, w0, w1, w2, w3, w4, w5, w6, w7);
        uint4 v = h4[(unsigned)si * 16u + cbase];
        CONS(v, wi)
    }
    if (i < end) {  // tail: clamp index to last, zero weight for OOB slots
        int last = end - 1;
        int e1 = i + 1 > last ? last : i + 1;
        int e2 = i + 2 > last ? last : i + 2;
        int e3 = i + 3 > last ? last : i + 3;
        int e4 = i + 4 > last ? last : i + 4;
        int e5 = i + 5 > last ? last : i + 5;
        int e6 = i + 6 > last ? last : i + 6;
        int s0 = src[i], s1 = src[e1], s2 = src[e2], s3 = src[e3];
        int s4 = src[e4], s5 = src[e5], s6 = src[e6];
        float w0 = ew[i];
        float w1 = i + 1 < end ? ew[e1] : 0.f;
        float w2 = i + 2 < end ? ew[e2] : 0.f;
        float w3 = i + 3 < end ? ew[e3] : 0.f;
        float w4 = i + 4 < end ? ew[e4] : 0.f;
        float w5 = i + 5 < end ? ew[e5] : 0.f;
        float w6 = i + 6 < end ? ew[e6] : 0.f;
        int   si = SEL8(q, s0, s1, s2, s3, s4, s5, s6, s6);
        float wi = SEL8(q, w0, w1, w2, w3, w4, w5, w6, 0.f);
        uint4 v = h4[(unsigned)si * 16u + cbase];
        CONS(v, wi)
    }

    // combine edge slots: lanes {l^8, l^16, l^32} share the same cols
#pragma unroll
    for (int j = 0; j < 8; ++j) {
        acc[j] += __shfl_xor(acc[j], 8);
        acc[j] += __shfl_xor(acc[j], 16);
        acc[j] += __shfl_xor(acc[j], 32);
    }

    if (q == 0) {
        float4* op = (float4*)(out + (long)wid * 128 + slice * 64 + c * 8);
        op[0] = make_float4(acc[0], acc[1], acc[2], acc[3]);
        op[1] = make_float4(acc[4], acc[5], acc[6], acc[7]);
    }
}

extern "C" void kernel_launch(void* const* d_in, const int* in_sizes, int n_in,
                              void* d_out, int out_size, void* d_ws, size_t ws_size,
                              hipStream_t stream) {
    const float* x    = (const float*)d_in[0];
    const float* w    = (const float*)d_in[1];
    const float* ew   = (const float*)d_in[2];
    const int*   esrc = (const int*)d_in[3];
    const int*   edst = (const int*)d_in[4];
    float* out = (float*)d_out;

    unsigned short* hbf = (unsigned short*)d_ws;                       // 25.6 MB
    int* rowptr = (int*)((char*)d_ws + (size_t)NN * 128 * 2);          // +400 KB
    unsigned short* wbf = (unsigned short*)((char*)d_ws + (size_t)NN * 128 * 2 + 400016);

    convert_w<<<64, 256, 0, stream>>>(w, wbf);
    gemm_xwT<<<(NN / 16 + 3) / 4, 256, 0, stream>>>(x, wbf, hbf);
    build_rowptr<<<(NN + 1 + 255) / 256, 256, 0, stream>>>(edst, rowptr);
    // 25000 node-blocks (4 nodes each) x 2 slices; XCD-pinned mapping needs
    // groups of 8 blocks: 6250 groups x 8 = 50000 blocks. NN = 25000*4 exactly.
    aggregate<<<50000, 256, 0, stream>>>((const unsigned int*)hbf, ew, esrc, rowptr, out);
}

// Round 9
// 201.650 us; speedup vs baseline: 1.0435x; 1.0435x over previous
//
#include <hip/hip_runtime.h>

#define NN 100000
#define NE 3200000
#define FEAT 128
#define EMBED 128

typedef __attribute__((ext_vector_type(8))) __bf16 bf16x8;
typedef __attribute__((ext_vector_type(8))) unsigned short ushort8;
typedef __attribute__((ext_vector_type(4))) float f32x4;
typedef __attribute__((ext_vector_type(4))) unsigned int u32x4;

static __device__ __forceinline__ unsigned short f2bf(float f) {
    unsigned u = __float_as_uint(f);
    return (unsigned short)((u + 0x7FFFu + ((u >> 16) & 1u)) >> 16);  // RNE
}

// ---------------------------------------------------------------------------
// w fp32 [128][128] -> bf16 bits (ushort) [128][128]
// ---------------------------------------------------------------------------
__global__ void convert_w(const float* __restrict__ w, unsigned short* __restrict__ wbf) {
    int i = blockIdx.x * 256 + threadIdx.x;
    if (i < EMBED * FEAT) wbf[i] = f2bf(w[i]);
}

// ---------------------------------------------------------------------------
// h_bf[n][e] = bf16( sum_f x[n][f] * w[e][f] ), via mfma_f32_16x16x32_bf16.
// (unchanged -- memory-bound, ~15 us)
// ---------------------------------------------------------------------------
__global__ __launch_bounds__(256)
void gemm_xwT(const float* __restrict__ x, const unsigned short* __restrict__ wbf,
              unsigned short* __restrict__ hbf) {
    int wave = blockIdx.x * 4 + (threadIdx.x >> 6);
    long row0 = (long)wave * 16;
    if (row0 >= NN) return;
    int lane = threadIdx.x & 63;
    int r = lane & 15, kg = lane >> 4;

    const float4* x4 = (const float4*)x;  // [row*32 + fc4]
    const bf16x8* wb = (const bf16x8*)wbf;

    bf16x8 afr[4];
#pragma unroll
    for (int ks = 0; ks < 4; ++ks) {
        long base = (row0 + r) * 32 + ks * 8 + kg * 2;
        float4 v0 = x4[base];
        float4 v1 = x4[base + 1];
        float xf[8] = {v0.x, v0.y, v0.z, v0.w, v1.x, v1.y, v1.z, v1.w};
        ushort8 au;
#pragma unroll
        for (int e = 0; e < 8; ++e) au[e] = f2bf(xf[e]);
        afr[ks] = __builtin_bit_cast(bf16x8, au);
    }

    f32x4 acc[8];
#pragma unroll
    for (int nt = 0; nt < 8; ++nt) acc[nt] = (f32x4){0.f, 0.f, 0.f, 0.f};

#pragma unroll
    for (int nt = 0; nt < 8; ++nt) {
#pragma unroll
        for (int ks = 0; ks < 4; ++ks) {
            bf16x8 b = wb[(nt * 16 + r) * 16 + ks * 4 + kg];
            acc[nt] = __builtin_amdgcn_mfma_f32_16x16x32_bf16(afr[ks], b, acc[nt], 0, 0, 0);
        }
    }

#pragma unroll
    for (int nt = 0; nt < 8; ++nt) {
#pragma unroll
        for (int reg = 0; reg < 4; ++reg) {
            hbf[(row0 + kg * 4 + reg) * 128 + nt * 16 + r] = f2bf(acc[nt][reg]);
        }
    }
}

// ---------------------------------------------------------------------------
// CSR row offsets from sorted edge_dst via per-node lower_bound.
// ---------------------------------------------------------------------------
__global__ void build_rowptr(const int* __restrict__ dst, int* __restrict__ rowptr) {
    int n = blockIdx.x * blockDim.x + threadIdx.x;
    if (n > NN) return;
    int lo = 0, hi = NE;
    while (lo < hi) {
        int mid = (lo + hi) >> 1;
        if (dst[mid] < n) lo = mid + 1; else hi = mid;
    }
    rowptr[n] = lo;
}

// ---------------------------------------------------------------------------
// R4 structure (best measured: 151 us) + NON-TEMPORAL h gathers.
// One wave per destination node, 4 edges per load instruction.
// Lane l: edge slot q = l>>4, col-quad c = l&15 (cols c*8 .. c*8+7).
// One global_load_dwordx4 nt (bypasses L1 allocation -- the 25.6 MB random
// gather has ~0% L1 hit rate; nt shortens per-miss TCP occupancy) covers 4
// full bf16 h-rows = 1 KB/wave/instr. Metadata via wave-uniform scalar
// loads (cached -- real reuse). Per-lane 8 fp32 accumulators, statically
// indexed. Combine: 2 shfl_xor rounds once per wave; q==0 lanes store.
// Each out row written exactly once (covers poisoned d_out).
// ---------------------------------------------------------------------------
#define CONS(vj, wjv)                                                         \
    acc[0] += wjv * __uint_as_float(vj[0] << 16);                             \
    acc[1] += wjv * __uint_as_float(vj[0] & 0xFFFF0000u);                     \
    acc[2] += wjv * __uint_as_float(vj[1] << 16);                             \
    acc[3] += wjv * __uint_as_float(vj[1] & 0xFFFF0000u);                     \
    acc[4] += wjv * __uint_as_float(vj[2] << 16);                             \
    acc[5] += wjv * __uint_as_float(vj[2] & 0xFFFF0000u);                     \
    acc[6] += wjv * __uint_as_float(vj[3] << 16);                             \
    acc[7] += wjv * __uint_as_float(vj[3] & 0xFFFF0000u);

__global__ __launch_bounds__(256)
void aggregate(const unsigned int* __restrict__ h32, const float* __restrict__ ew,
               const int* __restrict__ src, const int* __restrict__ rowptr,
               float* __restrict__ out) {
    int wid = (int)((blockIdx.x * 256u + threadIdx.x) >> 6);
    int lane = threadIdx.x & 63;
    if (wid >= NN) return;
    int start = __builtin_amdgcn_readfirstlane(rowptr[wid]);
    int end   = __builtin_amdgcn_readfirstlane(rowptr[wid + 1]);

    int q = lane >> 4;
    int c = lane & 15;

    float acc[8];
#pragma unroll
    for (int j = 0; j < 8; ++j) acc[j] = 0.f;

    const u32x4* h4 = (const u32x4*)h32;  // [row*16 + c]

    int i = start;
    int nfull = (end - start) >> 2;
#pragma unroll 4
    for (int b = 0; b < nfull; ++b, i += 4) {
        // wave-uniform contiguous metadata -> scalar loads
        int s0 = src[i], s1 = src[i + 1], s2 = src[i + 2], s3 = src[i + 3];
        float w0 = ew[i], w1 = ew[i + 1], w2 = ew[i + 2], w3 = ew[i + 3];
        int   si = q == 0 ? s0 : (q == 1 ? s1 : (q == 2 ? s2 : s3));
        float wi = q == 0 ? w0 : (q == 1 ? w1 : (q == 2 ? w2 : w3));
        u32x4 v = __builtin_nontemporal_load(&h4[(unsigned)si * 16u + (unsigned)c]);
        CONS(v, wi)
    }
    if (i < end) {  // tail group: clamp index, zero weight for OOB slots
        int last = end - 1;
        int i1 = i + 1 < end ? i + 1 : last;
        int i2 = i + 2 < end ? i + 2 : last;
        int s0 = src[i], s1 = src[i1], s2 = src[i2];
        float w0 = ew[i];
        float w1 = i + 1 < end ? ew[i1] : 0.f;
        float w2 = i + 2 < end ? ew[i2] : 0.f;
        int   si = q == 0 ? s0 : (q == 1 ? s1 : s2);
        float wi = q == 0 ? w0 : (q == 1 ? w1 : (q == 2 ? w2 : 0.f));
        u32x4 v = __builtin_nontemporal_load(&h4[(unsigned)si * 16u + (unsigned)c]);
        CONS(v, wi)
    }

    // combine edge slots: lanes {l, l^16, l^32, l^48} share the same cols
#pragma unroll
    for (int j = 0; j < 8; ++j) {
        acc[j] += __shfl_xor(acc[j], 16);
        acc[j] += __shfl_xor(acc[j], 32);
    }

    if (q == 0) {
        float4* op = (float4*)(out + (long)wid * 128 + c * 8);
        op[0] = make_float4(acc[0], acc[1], acc[2], acc[3]);
        op[1] = make_float4(acc[4], acc[5], acc[6], acc[7]);
    }
}

extern "C" void kernel_launch(void* const* d_in, const int* in_sizes, int n_in,
                              void* d_out, int out_size, void* d_ws, size_t ws_size,
                              hipStream_t stream) {
    const float* x    = (const float*)d_in[0];
    const float* w    = (const float*)d_in[1];
    const float* ew   = (const float*)d_in[2];
    const int*   esrc = (const int*)d_in[3];
    const int*   edst = (const int*)d_in[4];
    float* out = (float*)d_out;

    unsigned short* hbf = (unsigned short*)d_ws;                       // 25.6 MB
    int* rowptr = (int*)((char*)d_ws + (size_t)NN * 128 * 2);          // +400 KB
    unsigned short* wbf = (unsigned short*)((char*)d_ws + (size_t)NN * 128 * 2 + 400016);

    convert_w<<<64, 256, 0, stream>>>(w, wbf);
    gemm_xwT<<<(NN / 16 + 3) / 4, 256, 0, stream>>>(x, wbf, hbf);
    build_rowptr<<<(NN + 1 + 255) / 256, 256, 0, stream>>>(edst, rowptr);
    aggregate<<<(NN * 64) / 256, 256, 0, stream>>>((const unsigned int*)hbf, ew, esrc, rowptr, out);
}

// Round 10
// 166.891 us; speedup vs baseline: 1.2608x; 1.2083x over previous
//
#include <hip/hip_runtime.h>

#define NN 100000
#define NE 3200000
#define FEAT 128
#define EMBED 128

typedef __attribute__((ext_vector_type(8))) __bf16 bf16x8;
typedef __attribute__((ext_vector_type(8))) unsigned short ushort8;
typedef __attribute__((ext_vector_type(4))) float f32x4;

static __device__ __forceinline__ unsigned short f2bf(float f) {
    unsigned u = __float_as_uint(f);
    return (unsigned short)((u + 0x7FFFu + ((u >> 16) & 1u)) >> 16);  // RNE
}

// ---------------------------------------------------------------------------
// w fp32 [128][128] -> bf16 bits (ushort) [128][128]
// ---------------------------------------------------------------------------
__global__ void convert_w(const float* __restrict__ w, unsigned short* __restrict__ wbf) {
    int i = blockIdx.x * 256 + threadIdx.x;
    if (i < EMBED * FEAT) wbf[i] = f2bf(w[i]);
}

// ---------------------------------------------------------------------------
// h_bf[n][e] = bf16( sum_f x[n][f] * w[e][f] ), via mfma_f32_16x16x32_bf16.
// One wave per 16-row stripe; memory-bound (~15 us).
// ---------------------------------------------------------------------------
__global__ __launch_bounds__(256)
void gemm_xwT(const float* __restrict__ x, const unsigned short* __restrict__ wbf,
              unsigned short* __restrict__ hbf) {
    int wave = blockIdx.x * 4 + (threadIdx.x >> 6);
    long row0 = (long)wave * 16;
    if (row0 >= NN) return;
    int lane = threadIdx.x & 63;
    int r = lane & 15, kg = lane >> 4;

    const float4* x4 = (const float4*)x;  // [row*32 + fc4]
    const bf16x8* wb = (const bf16x8*)wbf;

    bf16x8 afr[4];
#pragma unroll
    for (int ks = 0; ks < 4; ++ks) {
        long base = (row0 + r) * 32 + ks * 8 + kg * 2;
        float4 v0 = x4[base];
        float4 v1 = x4[base + 1];
        float xf[8] = {v0.x, v0.y, v0.z, v0.w, v1.x, v1.y, v1.z, v1.w};
        ushort8 au;
#pragma unroll
        for (int e = 0; e < 8; ++e) au[e] = f2bf(xf[e]);
        afr[ks] = __builtin_bit_cast(bf16x8, au);
    }

    f32x4 acc[8];
#pragma unroll
    for (int nt = 0; nt < 8; ++nt) acc[nt] = (f32x4){0.f, 0.f, 0.f, 0.f};

#pragma unroll
    for (int nt = 0; nt < 8; ++nt) {
#pragma unroll
        for (int ks = 0; ks < 4; ++ks) {
            bf16x8 b = wb[(nt * 16 + r) * 16 + ks * 4 + kg];
            acc[nt] = __builtin_amdgcn_mfma_f32_16x16x32_bf16(afr[ks], b, acc[nt], 0, 0, 0);
        }
    }

#pragma unroll
    for (int nt = 0; nt < 8; ++nt) {
#pragma unroll
        for (int reg = 0; reg < 4; ++reg) {
            hbf[(row0 + kg * 4 + reg) * 128 + nt * 16 + r] = f2bf(acc[nt][reg]);
        }
    }
}

// ---------------------------------------------------------------------------
// CSR row offsets from sorted edge_dst via per-node lower_bound.
// ---------------------------------------------------------------------------
__global__ void build_rowptr(const int* __restrict__ dst, int* __restrict__ rowptr) {
    int n = blockIdx.x * blockDim.x + threadIdx.x;
    if (n > NN) return;
    int lo = 0, hi = NE;
    while (lo < hi) {
        int mid = (lo + hi) >> 1;
        if (dst[mid] < n) lo = mid + 1; else hi = mid;
    }
    rowptr[n] = lo;
}

// ---------------------------------------------------------------------------
// R4 structure -- best measured (agg 151 us). One wave per destination node,
// 4 edges per load instruction. Lane l: edge slot q = l>>4, col-quad c =
// l&15. One global_load_dwordx4 covers 4 full bf16 h-rows = 1 KB/wave/instr.
// Metadata via wave-uniform scalar loads. Per-lane 8 fp32 accumulators,
// statically indexed. Combine: 2 shfl_xor rounds once per wave; q==0 lanes
// store. Each out row written exactly once (covers poisoned d_out).
//
// Measured limit (R4..R9 variants all 150-195 us): per-CU outstanding-miss
// capacity (~24 x 128B lines) x blended L2/L3 latency (~145 ns) = ~21
// GB/s/CU = ~5.4 TB/s chip-wide gather throughput. ILP/locality/cache-
// policy restructuring did not move it; nt and col-slicing regressed.
// ---------------------------------------------------------------------------
#define CONS(vj, wjv)                                                         \
    acc[0] += wjv * __uint_as_float(vj.x << 16);                              \
    acc[1] += wjv * __uint_as_float(vj.x & 0xFFFF0000u);                      \
    acc[2] += wjv * __uint_as_float(vj.y << 16);                              \
    acc[3] += wjv * __uint_as_float(vj.y & 0xFFFF0000u);                      \
    acc[4] += wjv * __uint_as_float(vj.z << 16);                              \
    acc[5] += wjv * __uint_as_float(vj.z & 0xFFFF0000u);                      \
    acc[6] += wjv * __uint_as_float(vj.w << 16);                              \
    acc[7] += wjv * __uint_as_float(vj.w & 0xFFFF0000u);

__global__ __launch_bounds__(256)
void aggregate(const unsigned int* __restrict__ h32, const float* __restrict__ ew,
               const int* __restrict__ src, const int* __restrict__ rowptr,
               float* __restrict__ out) {
    int wid = (int)((blockIdx.x * 256u + threadIdx.x) >> 6);
    int lane = threadIdx.x & 63;
    if (wid >= NN) return;
    int start = __builtin_amdgcn_readfirstlane(rowptr[wid]);
    int end   = __builtin_amdgcn_readfirstlane(rowptr[wid + 1]);

    int q = lane >> 4;
    int c = lane & 15;

    float acc[8];
#pragma unroll
    for (int j = 0; j < 8; ++j) acc[j] = 0.f;

    const uint4* h4 = (const uint4*)h32;  // [row*16 + c]

    int i = start;
    int nfull = (end - start) >> 2;
#pragma unroll 4
    for (int b = 0; b < nfull; ++b, i += 4) {
        // wave-uniform contiguous metadata -> scalar loads
        int s0 = src[i], s1 = src[i + 1], s2 = src[i + 2], s3 = src[i + 3];
        float w0 = ew[i], w1 = ew[i + 1], w2 = ew[i + 2], w3 = ew[i + 3];
        int   si = q == 0 ? s0 : (q == 1 ? s1 : (q == 2 ? s2 : s3));
        float wi = q == 0 ? w0 : (q == 1 ? w1 : (q == 2 ? w2 : w3));
        uint4 v = h4[(unsigned)si * 16u + (unsigned)c];
        CONS(v, wi)
    }
    if (i < end) {  // tail group: clamp index, zero weight for OOB slots
        int last = end - 1;
        int i1 = i + 1 < end ? i + 1 : last;
        int i2 = i + 2 < end ? i + 2 : last;
        int s0 = src[i], s1 = src[i1], s2 = src[i2];
        float w0 = ew[i];
        float w1 = i + 1 < end ? ew[i1] : 0.f;
        float w2 = i + 2 < end ? ew[i2] : 0.f;
        int   si = q == 0 ? s0 : (q == 1 ? s1 : s2);
        float wi = q == 0 ? w0 : (q == 1 ? w1 : (q == 2 ? w2 : 0.f));
        uint4 v = h4[(unsigned)si * 16u + (unsigned)c];
        CONS(v, wi)
    }

    // combine edge slots: lanes {l, l^16, l^32, l^48} share the same cols
#pragma unroll
    for (int j = 0; j < 8; ++j) {
        acc[j] += __shfl_xor(acc[j], 16);
        acc[j] += __shfl_xor(acc[j], 32);
    }

    if (q == 0) {
        float4* op = (float4*)(out + (long)wid * 128 + c * 8);
        op[0] = make_float4(acc[0], acc[1], acc[2], acc[3]);
        op[1] = make_float4(acc[4], acc[5], acc[6], acc[7]);
    }
}

extern "C" void kernel_launch(void* const* d_in, const int* in_sizes, int n_in,
                              void* d_out, int out_size, void* d_ws, size_t ws_size,
                              hipStream_t stream) {
    const float* x    = (const float*)d_in[0];
    const float* w    = (const float*)d_in[1];
    const float* ew   = (const float*)d_in[2];
    const int*   esrc = (const int*)d_in[3];
    const int*   edst = (const int*)d_in[4];
    float* out = (float*)d_out;

    unsigned short* hbf = (unsigned short*)d_ws;                       // 25.6 MB
    int* rowptr = (int*)((char*)d_ws + (size_t)NN * 128 * 2);          // +400 KB
    unsigned short* wbf = (unsigned short*)((char*)d_ws + (size_t)NN * 128 * 2 + 400016);

    convert_w<<<64, 256, 0, stream>>>(w, wbf);
    gemm_xwT<<<(NN / 16 + 3) / 4, 256, 0, stream>>>(x, wbf, hbf);
    build_rowptr<<<(NN + 1 + 255) / 256, 256, 0, stream>>>(edst, rowptr);
    aggregate<<<(NN * 64) / 256, 256, 0, stream>>>((const unsigned int*)hbf, ew, esrc, rowptr, out);
}